// Round 4
// baseline (142.203 us; speedup 1.0000x reference)
//
#include <hip/hip_runtime.h>
#include <hip/hip_bf16.h>

// AxialAtten B=4,H=W=C=64. Two passes: Q=xW^T+b; K=Q; V=xWv^T+b;
// O = sigmoid(QK^T/8) V; x = O*scale + x (with axis transpose).
// Pass1: xh[b,n,d] = x[b*BHWC + d*4096 + n]            (n=w*64+c, d=h)
// Pass2: xw[b,n,d] = x[b*BHWC + (n>>6)*4096 + d*64 + (n&63)]  (d=w)
//
// Q is pre-scaled by ALPHA = sqrt(0.125*log2(e)) so that
// sigmoid(S/8) = rcp(1 + exp2(-S')) with S' = (alpha Q)(alpha K)^T.

typedef __attribute__((ext_vector_type(8)))  short        short8;   // 8 bf16
typedef __attribute__((ext_vector_type(16))) float        f32x16;
typedef __attribute__((ext_vector_type(4)))  unsigned int u32x4;
typedef __attribute__((ext_vector_type(4)))  float        f32x4;

#define BHWC (4096 * 64)
#define ALPHA 0.42466089f   // sqrt(0.125 * 1.44269504)

__device__ __forceinline__ unsigned short f2bf(float f) {
    __hip_bfloat16 h = __float2bfloat16(f);          // HW RNE conversion
    union { __hip_bfloat16 h; unsigned short u; } c; c.h = h;
    return c.u;
}
__device__ __forceinline__ f32x16 zero16() {
    f32x16 z;
    #pragma unroll
    for (int r = 0; r < 16; ++r) z[r] = 0.0f;
    return z;
}

// ---------------------------------------------------------------------------
// MFMA projection: Q[b][n][o] bf16 (pre-scaled by ALPHA) and V^T[b][o][n] bf16.
// grid 256 = 4b x 64 n-tiles, block 256 (4 waves: 2 for Q, 2 for V).
// ---------------------------------------------------------------------------
template<int MODE>
__global__ __launch_bounds__(256) void proj_kernel(
    const float* __restrict__ xsrc,
    const float* __restrict__ Wq, const float* __restrict__ Bq,
    const float* __restrict__ Wv, const float* __restrict__ Bv,
    unsigned short* __restrict__ Qo, unsigned short* __restrict__ VTo)
{
    __shared__ __align__(16) unsigned short xbf[64 * 64];      // [n][d] XOR-swizzled
    __shared__ __align__(16) unsigned short wbf[2][64 * 64];   // [o][d] XOR-swizzled
    __shared__ __align__(16) unsigned short vst[64 * 66];      // [o][n] V re-stage

    const int b = blockIdx.x >> 6, tile = blockIdx.x & 63, n0 = tile << 6;
    const int tid = threadIdx.x;
    const float* xb = xsrc + b * BHWC;

    for (int i = tid; i < 4096; i += 256) {
        const int d = i >> 6, nl = i & 63;
        float v;
        if (MODE == 0) v = xb[d * 4096 + n0 + nl];
        else           v = xb[tile * 4096 + i];          // = tile*4096 + d*64 + c
        xbf[nl * 64 + (d ^ ((nl & 7) << 3))] = f2bf(v);
        wbf[0][d * 64 + (nl ^ ((d & 7) << 3))] = f2bf(Wq[i] * ALPHA);  // fold alpha
        wbf[1][d * 64 + (nl ^ ((d & 7) << 3))] = f2bf(Wv[i]);
    }
    __syncthreads();

    const int wave = tid >> 6, lane = tid & 63, l31 = lane & 31, hi = lane >> 5;
    const int mat = wave >> 1, nc = wave & 1;
    const int o = nc * 32 + l31;

    short8 bw[4];
    #pragma unroll
    for (int dc = 0; dc < 4; ++dc)
        bw[dc] = *(const short8*)&wbf[mat][o * 64 + ((dc * 16 + hi * 8) ^ ((o & 7) << 3))];

    f32x16 acc[2]; acc[0] = zero16(); acc[1] = zero16();
    #pragma unroll
    for (int dc = 0; dc < 4; ++dc) {
        #pragma unroll
        for (int mc = 0; mc < 2; ++mc) {
            const int row = mc * 32 + l31;
            const short8 a = *(const short8*)&xbf[row * 64 + ((dc * 16 + hi * 8) ^ ((row & 7) << 3))];
            acc[mc] = __builtin_amdgcn_mfma_f32_32x32x16_bf16(a, bw[dc], acc[mc], 0, 0, 0);
        }
    }
    const float bias = mat ? Bv[o] : (Bq[o] * ALPHA);

    if (mat == 0) {
        unsigned short* Qb = Qo + b * BHWC;
        #pragma unroll
        for (int mc = 0; mc < 2; ++mc)
            #pragma unroll
            for (int reg = 0; reg < 16; ++reg) {
                const int n = n0 + mc * 32 + (reg & 3) + 8 * (reg >> 2) + 4 * hi;
                Qb[n * 64 + o] = f2bf(acc[mc][reg] + bias);
            }
    } else {
        #pragma unroll
        for (int mc = 0; mc < 2; ++mc)
            #pragma unroll
            for (int reg = 0; reg < 16; ++reg) {
                const int nl2 = mc * 32 + (reg & 3) + 8 * (reg >> 2) + 4 * hi;
                vst[o * 66 + nl2] = f2bf(acc[mc][reg] + bias);
            }
    }
    __syncthreads();
    {   // coalesced V^T writeback: 4 threads per o-row
        unsigned short* VTb = VTo + b * BHWC;
        const int oo = tid >> 2, seg = tid & 3;
        u32x4 t0, t1;
        #pragma unroll
        for (int j = 0; j < 4; ++j) {
            t0[j] = *(const unsigned int*)&vst[oo * 66 + seg * 16 + j * 2];
            t1[j] = *(const unsigned int*)&vst[oo * 66 + seg * 16 + 8 + j * 2];
        }
        *(u32x4*)(VTb + oo * 4096 + n0 + seg * 16)     = t0;
        *(u32x4*)(VTb + oo * 4096 + n0 + seg * 16 + 8) = t1;
    }
}

// ---------------------------------------------------------------------------
// Fused sigmoid-attention, 32x32 MFMA, P via per-wave-private LDS tiles.
// grid 256 = 4b x 64 m-tiles(64 rows); block 1024 = 16 waves =
// (msub in {0,1}) x (kq in {0..7}); wave tile = 32m x 512k.
// Main loop is barrier-free (all LDS per-wave private); 8 k-partials per
// msub tree-reduced through LDS at the end (deterministic, no atomics).
// 4 waves/SIMD via launch_bounds VGPR cap.
// ---------------------------------------------------------------------------
template<int MODE>
__global__ __launch_bounds__(1024, 4) void attn_kernel(
    const unsigned short* __restrict__ Q,    // [b][4096][64] bf16, alpha-scaled (= K)
    const unsigned short* __restrict__ VT,   // [b][64][4096] bf16
    const float* __restrict__ xres,
    const float* __restrict__ wsc,
    float* __restrict__ xout)
{
    // union: Ps (16 waves x 4KB = 64KB, main loop) / Obuf (8 x 64x33 f32, reduce)
    __shared__ __align__(16) char smem[8 * 2112 * 4];   // 67584 B
    float* Obuf = (float*)smem;

    // XCD-aware swizzle: XCD x serves a contiguous half-batch (4MB K+V = its L2)
    const int bid = ((int)blockIdx.x & 7) * 32 + ((int)blockIdx.x >> 3);
    const int b = bid >> 6, mt = bid & 63, m0 = mt << 6;
    const int tid = threadIdx.x, wave = tid >> 6, lane = tid & 63;
    const int l31 = lane & 31, hi = lane >> 5;
    const int msub = wave & 1, kq = wave >> 1;     // adjacent waves share K/V lines
    const unsigned short* Qb  = Q  + b * BHWC;
    const unsigned short* VTb = VT + b * BHWC;
    char* Pw = smem + wave * 4096;                 // this wave's 32x64 bf16 P tile
    const int prow = l31 * 128, psw = (l31 & 7) << 4;

    // Q B-fragments for this wave's 32 m-rows (persistent): B[k=d][col=m]
    const int mrow = m0 + msub * 32 + l31;
    short8 qf[4];
    #pragma unroll
    for (int dc = 0; dc < 4; ++dc)
        qf[dc] = *(const short8*)(Qb + mrow * 64 + dc * 16 + hi * 8);

    f32x16 acc[2]; acc[0] = zero16(); acc[1] = zero16();   // O[32m][64d]

    // sigmoid(S/8) = rcp(1 + exp2(-S')), then pack pairs -> u32 -> swizzled LDS
    auto SIGSTORE = [&](const f32x16& s, int krc) {
        #pragma unroll
        for (int j = 0; j < 8; ++j) {
            const float p0 = __builtin_amdgcn_rcpf(1.0f + exp2f(-s[2 * j]));
            const float p1 = __builtin_amdgcn_rcpf(1.0f + exp2f(-s[2 * j + 1]));
            const unsigned int pk = (unsigned int)f2bf(p0) | ((unsigned int)f2bf(p1) << 16);
            const int kr = krc * 32 + 2 * (j & 1) + 8 * (j >> 1) + 4 * hi;
            *(unsigned int*)(Pw + ((prow + kr * 2) ^ psw)) = pk;
        }
    };

    #pragma unroll 1
    for (int i = 0; i < 8; ++i) {
        const int kbase = kq * 512 + i * 64;

        // ---- krc 0: S^T[kr][m] = sum_d K[kr][d] Q[m][d] ----
        short8 kf[4];
        #pragma unroll
        for (int dc = 0; dc < 4; ++dc)
            kf[dc] = *(const short8*)(Qb + (kbase + l31) * 64 + dc * 16 + hi * 8);
        f32x16 s0 = zero16();
        #pragma unroll
        for (int dc = 0; dc < 4; ++dc)
            s0 = __builtin_amdgcn_mfma_f32_32x32x16_bf16(kf[dc], qf[dc], s0, 0, 0, 0);
        SIGSTORE(s0, 0);

        // ---- krc 1 ----
        #pragma unroll
        for (int dc = 0; dc < 4; ++dc)
            kf[dc] = *(const short8*)(Qb + (kbase + 32 + l31) * 64 + dc * 16 + hi * 8);
        f32x16 s1 = zero16();
        #pragma unroll
        for (int dc = 0; dc < 4; ++dc)
            s1 = __builtin_amdgcn_mfma_f32_32x32x16_bf16(kf[dc], qf[dc], s1, 0, 0, 0);

        // issue V loads now; L2 latency hides under krc1's sigmoid
        short8 vf[4][2];   // B[k][col=d]
        #pragma unroll
        for (int kc = 0; kc < 4; ++kc)
            #pragma unroll
            for (int dc2 = 0; dc2 < 2; ++dc2)
                vf[kc][dc2] = *(const short8*)(VTb + (dc2 * 32 + l31) * 4096 + kbase + kc * 16 + hi * 8);

        SIGSTORE(s1, 1);

        // ---- read P A-frags back (wave-private: no barrier) ----
        short8 pf[4];
        #pragma unroll
        for (int kc = 0; kc < 4; ++kc)
            pf[kc] = *(const short8*)(Pw + ((prow + kc * 32 + hi * 16) ^ psw));

        // ---- O[m][d] += P[m][k] V[k][d] ----
        #pragma unroll
        for (int kc = 0; kc < 4; ++kc)
            #pragma unroll
            for (int dc2 = 0; dc2 < 2; ++dc2)
                acc[dc2] = __builtin_amdgcn_mfma_f32_32x32x16_bf16(pf[kc], vf[kc][dc2], acc[dc2], 0, 0, 0);
    }

    // ---- tree-reduce 8 kq-partials per msub through LDS (aliases Ps) ----
    __syncthreads();                       // all waves done with their Ps
    if (kq < 4) {
        float* Ob = Obuf + (msub * 4 + kq) * 2112;
        #pragma unroll
        for (int dc2 = 0; dc2 < 2; ++dc2)
            #pragma unroll
            for (int reg = 0; reg < 16; ++reg)
                Ob[(dc2 * 32 + l31) * 33 + (reg & 3) + 8 * (reg >> 2) + 4 * hi] = acc[dc2][reg];
    }
    __syncthreads();
    if (kq >= 4) {
        float* Ob = Obuf + (msub * 4 + kq - 4) * 2112;
        #pragma unroll
        for (int dc2 = 0; dc2 < 2; ++dc2)
            #pragma unroll
            for (int reg = 0; reg < 16; ++reg)
                Ob[(dc2 * 32 + l31) * 33 + (reg & 3) + 8 * (reg >> 2) + 4 * hi] += acc[dc2][reg];
    }
    __syncthreads();

    // ---- epilogue: sum 4 slots + residual; 1024 threads x 4 outputs ----
    const float w = wsc[0];
    const int d = tid >> 4, ms = (tid & 15) << 2;
    const int msb = ms >> 5, mloc = ms & 31;
    long base;
    if (MODE == 0) base = (long)b * BHWC + d * 4096 + m0 + ms;
    else           base = (long)b * BHWC + mt * 4096 + d * 64 + ms;
    const float* O0 = Obuf + (msb * 4 + 0) * 2112 + d * 33 + mloc;
    const float* O1 = Obuf + (msb * 4 + 1) * 2112 + d * 33 + mloc;
    const float* O2 = Obuf + (msb * 4 + 2) * 2112 + d * 33 + mloc;
    const float* O3 = Obuf + (msb * 4 + 3) * 2112 + d * 33 + mloc;
    f32x4 r = *(const f32x4*)(xres + base);
    f32x4 o;
    #pragma unroll
    for (int j = 0; j < 4; ++j)
        o[j] = (O0[j] + O1[j] + O2[j] + O3[j]) * w + r[j];
    *(f32x4*)(xout + base) = o;
}

// ---------------------------------------------------------------------------
extern "C" void kernel_launch(void* const* d_in, const int* in_sizes, int n_in,
                              void* d_out, int out_size, void* d_ws, size_t ws_size,
                              hipStream_t stream) {
    const float* x    = (const float*)d_in[0];
    const float* hq_w = (const float*)d_in[1];
    const float* hq_b = (const float*)d_in[2];
    const float* hv_w = (const float*)d_in[3];
    const float* hv_b = (const float*)d_in[4];
    const float* wq_w = (const float*)d_in[5];
    const float* wq_b = (const float*)d_in[6];
    const float* wv_w = (const float*)d_in[7];
    const float* wv_b = (const float*)d_in[8];
    const float* h_wt = (const float*)d_in[9];
    const float* w_wt = (const float*)d_in[10];
    float* out = (float*)d_out;

    unsigned short* Qws  = (unsigned short*)d_ws;          // 2MB (alpha-scaled Q)
    unsigned short* VTws = Qws + 4 * BHWC;                 // 2MB

    proj_kernel<0><<<256, 256, 0, stream>>>(x, hq_w, hq_b, hv_w, hv_b, Qws, VTws);
    attn_kernel<0><<<256, 1024, 0, stream>>>(Qws, VTws, x, h_wt, out);
    proj_kernel<1><<<256, 256, 0, stream>>>(out, wq_w, wq_b, wv_w, wv_b, Qws, VTws);
    attn_kernel<1><<<256, 1024, 0, stream>>>(Qws, VTws, out, w_wt, out);
}